// Round 10
// baseline (167.119 us; speedup 1.0000x reference)
//
#include <hip/hip_runtime.h>
#include <hip/hip_bf16.h>

typedef unsigned short ushort_t;
typedef __attribute__((ext_vector_type(4))) float f32x4;
typedef __attribute__((ext_vector_type(8))) __bf16 bfrag;

#define MFMA16(a,b,c) __builtin_amdgcn_mfma_f32_16x16x32_bf16((a),(b),(c),0,0,0)

#define HID 768
#define NH 12
#define SEQ 4096
#define QSCALE 0.18033688011112042f  /* 0.125 * log2(e): folds 1/sqrt(64) and exp->exp2 */

// Per-wave waits on outstanding global_load_lds (vmcnt is per-wave; FIFO).
// vmcnt(0) before a handoff barrier = round-6 correctness fix.
// vmcnt(4) = counted variant (T4): all but the 4 newest DMAs have landed,
// so the CURRENT tile is complete while the NEXT tile's 4 stay in flight.
#define WAIT_VMCNT0() asm volatile("s_waitcnt vmcnt(0)" ::: "memory")
#define WAIT_VMCNT4() asm volatile("s_waitcnt vmcnt(4)" ::: "memory")

__device__ __forceinline__ unsigned short f2bf(float x) {
  union { float f; unsigned u; } v; v.f = x;
  unsigned r = v.u + 0x7fffu + ((v.u >> 16) & 1u);  // RTNE
  return (unsigned short)(r >> 16);
}

typedef const unsigned char __attribute__((address_space(1)))* gas1_t;
typedef unsigned char __attribute__((address_space(3)))* las3_t;
__device__ __forceinline__ void gload_lds16(const void* g, void* l) {
  __builtin_amdgcn_global_load_lds((gas1_t)(unsigned long long)g,
                                   (las3_t)(unsigned)(unsigned long long)l,
                                   16, 0, 0);
}

__device__ __forceinline__ f32x4 zero4() { f32x4 z = {0.f, 0.f, 0.f, 0.f}; return z; }

// ---------------------------------------------------------------- kernel 1
__global__ __launch_bounds__(256) void cvt_hidden(const float* __restrict__ hs,
                                                  ushort_t* __restrict__ A) {
  int i = blockIdx.x * 256 + threadIdx.x;
  float4 v = ((const float4*)hs)[i];
  ushort4 o;
  o.x = f2bf(v.x); o.y = f2bf(v.y); o.z = f2bf(v.z); o.w = f2bf(v.w);
  ((ushort4*)A)[i] = o;
}

// ---------------------------------------------------------------- kernel 2
__global__ __launch_bounds__(256) void transpose_w(const float* __restrict__ Wq,
                                                   const float* __restrict__ Wk,
                                                   const float* __restrict__ Wv,
                                                   ushort_t* __restrict__ Wt) {
  const int z = blockIdx.z;
  const float* W = (z == 0) ? Wq : ((z == 1) ? Wk : Wv);
  const int k0 = blockIdx.x * 64, n0 = blockIdx.y * 64;
  __shared__ float tile[64][65];
  const int t = threadIdx.x;
  const int c4 = (t & 15) * 4;
  const int r = t >> 4;
#pragma unroll
  for (int it = 0; it < 4; ++it) {
    int rr = r + it * 16;
    float4 v = *(const float4*)&W[(size_t)(k0 + rr) * HID + n0 + c4];
    tile[c4 + 0][rr] = v.x; tile[c4 + 1][rr] = v.y;
    tile[c4 + 2][rr] = v.z; tile[c4 + 3][rr] = v.w;
  }
  __syncthreads();
#pragma unroll
  for (int it = 0; it < 4; ++it) {
    int nl = r + it * 16;
    ushort4 o;
    o.x = f2bf(tile[nl][c4 + 0]); o.y = f2bf(tile[nl][c4 + 1]);
    o.z = f2bf(tile[nl][c4 + 2]); o.w = f2bf(tile[nl][c4 + 3]);
    *(ushort4*)&Wt[((size_t)z * HID + n0 + nl) * HID + k0 + c4] = o;
  }
}

// ---------------------------------------------------------------- kernel 3
// V epilogue stores k-columns permuted within each 32-block:
// V_true col (32K + 16A + 4G + B) stored at (32K + 8G + 4A + B), matching the
// natural in-register k-order of the attn P fragments.  Bijective, zero cost.
__global__ __launch_bounds__(256) void qkv_gemm(const ushort_t* __restrict__ A,
                                                const ushort_t* __restrict__ Wt,
                                                const float* __restrict__ bq,
                                                const float* __restrict__ bk,
                                                const float* __restrict__ bv,
                                                ushort_t* __restrict__ Qh,
                                                ushort_t* __restrict__ Kh,
                                                ushort_t* __restrict__ Vt) {
  __shared__ ushort_t Als[128 * 64];
  __shared__ ushort_t Bls[128 * 64];
  const int z = blockIdx.z;
  const int m0 = blockIdx.x * 128, n0 = blockIdx.y * 128;
  const ushort_t* Wz = Wt + (size_t)z * HID * HID;
  const float* bias = (z == 0) ? bq : ((z == 1) ? bk : bv);
  const int t = threadIdx.x, w = t >> 6, lane = t & 63;
  const int g = lane >> 4, qc = lane & 15;
  const int srow = lane >> 3, sch = lane & 7;
  const int wm = w >> 1, wn = w & 1;

  f32x4 acc[4][4];
#pragma unroll
  for (int mt = 0; mt < 4; ++mt)
#pragma unroll
    for (int nt = 0; nt < 4; ++nt) acc[mt][nt] = zero4();

  for (int kt = 0; kt < 12; ++kt) {
    const int k0 = kt * 64;
#pragma unroll
    for (int i = 0; i < 4; ++i) {
      int row = w * 32 + i * 8 + srow;
      int chA = sch ^ (srow & 7);
      gload_lds16(&A[(size_t)(m0 + row) * HID + k0 + chA * 8],
                  &Als[(w * 32 + i * 8) * 64]);
      gload_lds16(&Wz[(size_t)(n0 + row) * HID + k0 + chA * 8],
                  &Bls[(w * 32 + i * 8) * 64]);
    }
    WAIT_VMCNT0();     // all of THIS wave's DMA landed; barrier makes it global
    __syncthreads();
#pragma unroll
    for (int kk = 0; kk < 2; ++kk) {
      bfrag af[4], bf_[4];
#pragma unroll
      for (int mt = 0; mt < 4; ++mt) {
        int row = wm * 64 + mt * 16 + qc;
        af[mt] = *(const bfrag*)((const char*)Als + row * 128 +
                                 (((kk * 4 + g) ^ (qc & 7)) << 4));
      }
#pragma unroll
      for (int nt = 0; nt < 4; ++nt) {
        int row = wn * 64 + nt * 16 + qc;
        bf_[nt] = *(const bfrag*)((const char*)Bls + row * 128 +
                                  (((kk * 4 + g) ^ (qc & 7)) << 4));
      }
#pragma unroll
      for (int mt = 0; mt < 4; ++mt)
#pragma unroll
        for (int nt = 0; nt < 4; ++nt)
          acc[mt][nt] = MFMA16(af[mt], bf_[nt], acc[mt][nt]);
    }
    __syncthreads();
  }

#pragma unroll
  for (int mt = 0; mt < 4; ++mt) {
#pragma unroll
    for (int nt = 0; nt < 4; ++nt) {
      int n = n0 + wn * 64 + nt * 16 + qc;
      int head = n >> 6, d = n & 63;
      float bb = bias[n];
      int mB = m0 + wm * 64 + mt * 16 + 4 * g;
      int bidx = mB >> 12, s0 = mB & 4095;
      f32x4 a = acc[mt][nt];
      if (z == 2) {
        ushort4 o;
        o.x = f2bf(a[0] + bb); o.y = f2bf(a[1] + bb);
        o.z = f2bf(a[2] + bb); o.w = f2bf(a[3] + bb);
        // permuted storage column: (32K|16A|4G|B) -> (32K|8G|4A|B); B=0 here
        int scol = (s0 & ~31) | (((s0 >> 2) & 3) << 3) | (((s0 >> 4) & 1) << 2);
        *(ushort4*)&Vt[((size_t)((bidx * NH + head) * 64 + d)) * SEQ + scol] = o;
      } else {
        ushort_t* dst = (z == 0) ? Qh : Kh;
        float sc = (z == 0) ? QSCALE : 1.0f;
        size_t base = (size_t)(bidx * NH + head) * SEQ;
#pragma unroll
        for (int i = 0; i < 4; ++i)
          dst[(base + s0 + i) * 64 + d] = f2bf((a[i] + bb) * sc);
      }
    }
  }
}

// ---------------------------------------------------------------- kernel 4
// Flash attention, no-max softmax, zero-shuffle P (V-permutation supplies
// the k-order the in-register P fragments carry).  Round-10 change: the
// validated round-6 compute structure (4 waves x 32q, full k -- best so far)
// with TRIPLE-BUFFERED staging and COUNTED vmcnt (T4): prologue stages tiles
// 0,1; each iter waits vmcnt(4) (drains THIS tile's 4 DMAs, FIFO, while the
// next tile's 4 stay in flight across the barrier), then stages tile kt+2
// into the third buffer.  Round 6 drained vmcnt to 0 every iter -- that
// serialized prefetch latency into every epoch (both pipes stuck ~50%).
// Correctness: per-wave FIFO wait + barrier (round-6 discipline, counted);
// the buffer being overwritten was fully read (its readers passed the
// barrier); no staging after kt=61 and vmcnt(0) at kt=63 -> nothing in
// flight at s_endpgm.
__global__ __launch_bounds__(256, 3) void attn_kernel(const ushort_t* __restrict__ Qh,
                                                      const ushort_t* __restrict__ Kh,
                                                      const ushort_t* __restrict__ Vt,
                                                      float* __restrict__ out) {
  const int bh = blockIdx.y;
  const int b = bh / NH, head = bh - b * NH;
  const int t = threadIdx.x, w = t >> 6, lane = t & 63;
  const int g = lane >> 4, qc = lane & 15;
  const ushort_t* Qb = Qh + (size_t)bh * SEQ * 64;
  const ushort_t* Kb = Kh + (size_t)bh * SEQ * 64;
  const ushort_t* Vb = Vt + (size_t)bh * 64 * SEQ;
  const int q0 = blockIdx.x * 128 + w * 32;

  __shared__ ushort_t Kls[3][4096];  // [buf][64 krow x 64 d], (r&7)-swizzled 16B chunks
  __shared__ ushort_t Vls[3][4096];  // [buf][64 d x 64 k],   (r&7)-swizzled 16B chunks

  int jr[2], jc[2];
#pragma unroll
  for (int i = 0; i < 2; ++i) {
    int j = w * 128 + i * 64 + lane;
    jr[i] = j >> 3;
    jc[i] = (j & 7) ^ (jr[i] & 7);
  }

  bfrag qv[2][2];
#pragma unroll
  for (int qf = 0; qf < 2; ++qf)
#pragma unroll
    for (int dd = 0; dd < 2; ++dd)
      qv[qf][dd] = *(const bfrag*)&Qb[(size_t)(q0 + qf * 16 + qc) * 64 + dd * 32 + g * 8];

  f32x4 o[2][4];
  f32x4 lacc[2];
#pragma unroll
  for (int qf = 0; qf < 2; ++qf) {
    lacc[qf] = zero4();
#pragma unroll
    for (int dt = 0; dt < 4; ++dt) o[qf][dt] = zero4();
  }
  bfrag ones;
#pragma unroll
  for (int j = 0; j < 8; ++j) ones[j] = (__bf16)1.0f;

  // prologue: stage tiles 0 and 1 into bufs 0 and 1 (8 DMAs outstanding)
#pragma unroll
  for (int tt = 0; tt < 2; ++tt) {
    const int kb = tt * 64;
#pragma unroll
    for (int i = 0; i < 2; ++i) {
      gload_lds16(&Kb[(size_t)(kb + jr[i]) * 64 + jc[i] * 8],
                  &Kls[tt][(w * 128 + i * 64) * 8]);
      gload_lds16(&Vb[(size_t)jr[i] * SEQ + kb + jc[i] * 8],
                  &Vls[tt][(w * 128 + i * 64) * 8]);
    }
  }

  int cur = 0;
  for (int kt = 0; kt < 64; ++kt) {
    if (kt < 63) WAIT_VMCNT4();   // tile kt landed; tile kt+1 stays in flight
    else         WAIT_VMCNT0();   // last iter: drain everything
    __syncthreads();              // ...for every wave: buf `cur` fully staged
    if (kt < 62) {                // stage tile kt+2 into the buffer freed at kt-1
      const int sbuf = (cur >= 1) ? cur - 1 : cur + 2;  // (cur+2)%3
      const int kbn = (kt + 2) * 64;
#pragma unroll
      for (int i = 0; i < 2; ++i) {
        gload_lds16(&Kb[(size_t)(kbn + jr[i]) * 64 + jc[i] * 8],
                    &Kls[sbuf][(w * 128 + i * 64) * 8]);
        gload_lds16(&Vb[(size_t)jr[i] * SEQ + kbn + jc[i] * 8],
                    &Vls[sbuf][(w * 128 + i * 64) * 8]);
      }
    }
    const ushort_t* Kc = Kls[cur];
    const ushort_t* Vc = Vls[cur];

    // K fragments (round-2-validated addresses), hoisted across both qf
    bfrag ak[4][2];
#pragma unroll
    for (int s = 0; s < 4; ++s) {
      const int r = s * 16 + qc;
      ak[s][0] = *(const bfrag*)&Kc[r * 64 + ((g ^ (qc & 7)) * 8)];
      ak[s][1] = *(const bfrag*)&Kc[r * 64 + (((4 + g) ^ (qc & 7)) * 8)];
    }

    // S^T slabs -> P fragments, fully in-register (natural k-order)
    bfrag bpq[2][2];
#pragma unroll
    for (int qf = 0; qf < 2; ++qf) {
      f32x4 st[4];
      __builtin_amdgcn_s_setprio(1);
#pragma unroll
      for (int s = 0; s < 4; ++s) {
        f32x4 zz = zero4();
        zz = MFMA16(ak[s][0], qv[qf][0], zz);
        st[s] = MFMA16(ak[s][1], qv[qf][1], zz);
      }
      __builtin_amdgcn_s_setprio(0);
#pragma unroll
      for (int i = 0; i < 4; ++i) {
        bpq[qf][0][i]     = (__bf16)__builtin_amdgcn_exp2f(st[0][i]);
        bpq[qf][0][4 + i] = (__bf16)__builtin_amdgcn_exp2f(st[1][i]);
        bpq[qf][1][i]     = (__bf16)__builtin_amdgcn_exp2f(st[2][i]);
        bpq[qf][1][4 + i] = (__bf16)__builtin_amdgcn_exp2f(st[3][i]);
      }
      lacc[qf] = MFMA16(ones, bpq[qf][0], lacc[qf]);
      lacc[qf] = MFMA16(ones, bpq[qf][1], lacc[qf]);
    }

    // O^T += Vperm.P^T   (av read once, shared by both qf)
    __builtin_amdgcn_s_setprio(1);
#pragma unroll
    for (int kk = 0; kk < 2; ++kk) {
#pragma unroll
      for (int dt = 0; dt < 4; ++dt) {
        bfrag av = *(const bfrag*)&Vc[(dt * 16 + qc) * 64 + (((kk * 4 + g) ^ (qc & 7)) * 8)];
        o[0][dt] = MFMA16(av, bpq[0][kk], o[0][dt]);
        o[1][dt] = MFMA16(av, bpq[1][kk], o[1][dt]);
      }
    }
    __builtin_amdgcn_s_setprio(0);

    cur = (cur == 2) ? 0 : cur + 1;
  }

  // epilogue: O^T layout row d = dt*16+4g+i, col q = qc; l identical in every reg
#pragma unroll
  for (int qf = 0; qf < 2; ++qf) {
    float inv = 1.0f / lacc[qf][0];
    int qrow = q0 + qf * 16 + qc;
    float* orow = out + (size_t)(b * SEQ + qrow) * HID + head * 64;
#pragma unroll
    for (int dt = 0; dt < 4; ++dt) {
      float4 vv;
      vv.x = o[qf][dt][0] * inv; vv.y = o[qf][dt][1] * inv;
      vv.z = o[qf][dt][2] * inv; vv.w = o[qf][dt][3] * inv;
      *(float4*)(orow + dt * 16 + 4 * g) = vv;
    }
  }
}

// ---------------------------------------------------------------- launch
extern "C" void kernel_launch(void* const* d_in, const int* in_sizes, int n_in,
                              void* d_out, int out_size, void* d_ws, size_t ws_size,
                              hipStream_t stream) {
  (void)in_sizes; (void)n_in; (void)out_size; (void)ws_size;
  const float* hs = (const float*)d_in[0];
  const float* Wq = (const float*)d_in[1];
  const float* bq = (const float*)d_in[2];
  const float* Wk = (const float*)d_in[3];
  const float* bk = (const float*)d_in[4];
  const float* Wv = (const float*)d_in[5];
  const float* bv = (const float*)d_in[6];
  float* out = (float*)d_out;

  char* ws = (char*)d_ws;
  ushort_t* Abf = (ushort_t*)ws;                               // 12582912 B
  ushort_t* Wt  = (ushort_t*)(ws + 12582912);                  //  3538944 B
  ushort_t* Qh  = (ushort_t*)(ws + 12582912 + 3538944);        // 12582912 B
  ushort_t* Kh  = Qh + 6291456;
  ushort_t* Vt  = Kh + 6291456;

  cvt_hidden<<<6144, 256, 0, stream>>>(hs, Abf);
  transpose_w<<<dim3(12, 12, 3), 256, 0, stream>>>(Wq, Wk, Wv, Wt);
  qkv_gemm<<<dim3(64, 6, 3), 256, 0, stream>>>(Abf, Wt, bq, bk, bv, Qh, Kh, Vt);
  attn_kernel<<<dim3(32, 24), 256, 0, stream>>>(Qh, Kh, Vt, out);
}

// Round 11
// 165.174 us; speedup vs baseline: 1.0118x; 1.0118x over previous
//
#include <hip/hip_runtime.h>
#include <hip/hip_bf16.h>

typedef unsigned short ushort_t;
typedef __attribute__((ext_vector_type(4))) float f32x4;
typedef __attribute__((ext_vector_type(8))) __bf16 bfrag;

#define MFMA16(a,b,c) __builtin_amdgcn_mfma_f32_16x16x32_bf16((a),(b),(c),0,0,0)

#define HID 768
#define NH 12
#define SEQ 4096
#define QSCALE 0.18033688011112042f  /* 0.125 * log2(e): folds 1/sqrt(64) and exp->exp2 */

// Per-wave drain of outstanding global_load_lds BEFORE a barrier.
// __syncthreads() alone does NOT guarantee another wave's LDS-DMA has landed:
// vmcnt is per-wave and the waitcnt pass only protects same-wave reads.
#define WAIT_VMCNT0() asm volatile("s_waitcnt vmcnt(0)" ::: "memory")

__device__ __forceinline__ unsigned short f2bf(float x) {
  union { float f; unsigned u; } v; v.f = x;
  unsigned r = v.u + 0x7fffu + ((v.u >> 16) & 1u);  // RTNE
  return (unsigned short)(r >> 16);
}

typedef const unsigned char __attribute__((address_space(1)))* gas1_t;
typedef unsigned char __attribute__((address_space(3)))* las3_t;
__device__ __forceinline__ void gload_lds16(const void* g, void* l) {
  __builtin_amdgcn_global_load_lds((gas1_t)(unsigned long long)g,
                                   (las3_t)(unsigned)(unsigned long long)l,
                                   16, 0, 0);
}

__device__ __forceinline__ f32x4 zero4() { f32x4 z = {0.f, 0.f, 0.f, 0.f}; return z; }

// ---------------------------------------------------------------- kernel 1
__global__ __launch_bounds__(256) void cvt_hidden(const float* __restrict__ hs,
                                                  ushort_t* __restrict__ A) {
  int i = blockIdx.x * 256 + threadIdx.x;
  float4 v = ((const float4*)hs)[i];
  ushort4 o;
  o.x = f2bf(v.x); o.y = f2bf(v.y); o.z = f2bf(v.z); o.w = f2bf(v.w);
  ((ushort4*)A)[i] = o;
}

// ---------------------------------------------------------------- kernel 2
__global__ __launch_bounds__(256) void transpose_w(const float* __restrict__ Wq,
                                                   const float* __restrict__ Wk,
                                                   const float* __restrict__ Wv,
                                                   ushort_t* __restrict__ Wt) {
  const int z = blockIdx.z;
  const float* W = (z == 0) ? Wq : ((z == 1) ? Wk : Wv);
  const int k0 = blockIdx.x * 64, n0 = blockIdx.y * 64;
  __shared__ float tile[64][65];
  const int t = threadIdx.x;
  const int c4 = (t & 15) * 4;
  const int r = t >> 4;
#pragma unroll
  for (int it = 0; it < 4; ++it) {
    int rr = r + it * 16;
    float4 v = *(const float4*)&W[(size_t)(k0 + rr) * HID + n0 + c4];
    tile[c4 + 0][rr] = v.x; tile[c4 + 1][rr] = v.y;
    tile[c4 + 2][rr] = v.z; tile[c4 + 3][rr] = v.w;
  }
  __syncthreads();
#pragma unroll
  for (int it = 0; it < 4; ++it) {
    int nl = r + it * 16;
    ushort4 o;
    o.x = f2bf(tile[nl][c4 + 0]); o.y = f2bf(tile[nl][c4 + 1]);
    o.z = f2bf(tile[nl][c4 + 2]); o.w = f2bf(tile[nl][c4 + 3]);
    *(ushort4*)&Wt[((size_t)z * HID + n0 + nl) * HID + k0 + c4] = o;
  }
}

// ---------------------------------------------------------------- kernel 3
// V epilogue stores k-columns permuted within each 32-block:
// V_true col (32K + 16A + 4G + B) stored at (32K + 8G + 4A + B), matching the
// natural in-register k-order of the attn P fragments.  Bijective, zero cost.
__global__ __launch_bounds__(256) void qkv_gemm(const ushort_t* __restrict__ A,
                                                const ushort_t* __restrict__ Wt,
                                                const float* __restrict__ bq,
                                                const float* __restrict__ bk,
                                                const float* __restrict__ bv,
                                                ushort_t* __restrict__ Qh,
                                                ushort_t* __restrict__ Kh,
                                                ushort_t* __restrict__ Vt) {
  __shared__ ushort_t Als[128 * 64];
  __shared__ ushort_t Bls[128 * 64];
  const int z = blockIdx.z;
  const int m0 = blockIdx.x * 128, n0 = blockIdx.y * 128;
  const ushort_t* Wz = Wt + (size_t)z * HID * HID;
  const float* bias = (z == 0) ? bq : ((z == 1) ? bk : bv);
  const int t = threadIdx.x, w = t >> 6, lane = t & 63;
  const int g = lane >> 4, qc = lane & 15;
  const int srow = lane >> 3, sch = lane & 7;
  const int wm = w >> 1, wn = w & 1;

  f32x4 acc[4][4];
#pragma unroll
  for (int mt = 0; mt < 4; ++mt)
#pragma unroll
    for (int nt = 0; nt < 4; ++nt) acc[mt][nt] = zero4();

  for (int kt = 0; kt < 12; ++kt) {
    const int k0 = kt * 64;
#pragma unroll
    for (int i = 0; i < 4; ++i) {
      int row = w * 32 + i * 8 + srow;
      int chA = sch ^ (srow & 7);
      gload_lds16(&A[(size_t)(m0 + row) * HID + k0 + chA * 8],
                  &Als[(w * 32 + i * 8) * 64]);
      gload_lds16(&Wz[(size_t)(n0 + row) * HID + k0 + chA * 8],
                  &Bls[(w * 32 + i * 8) * 64]);
    }
    WAIT_VMCNT0();     // all of THIS wave's DMA landed; barrier makes it global
    __syncthreads();
#pragma unroll
    for (int kk = 0; kk < 2; ++kk) {
      bfrag af[4], bf_[4];
#pragma unroll
      for (int mt = 0; mt < 4; ++mt) {
        int row = wm * 64 + mt * 16 + qc;
        af[mt] = *(const bfrag*)((const char*)Als + row * 128 +
                                 (((kk * 4 + g) ^ (qc & 7)) << 4));
      }
#pragma unroll
      for (int nt = 0; nt < 4; ++nt) {
        int row = wn * 64 + nt * 16 + qc;
        bf_[nt] = *(const bfrag*)((const char*)Bls + row * 128 +
                                  (((kk * 4 + g) ^ (qc & 7)) << 4));
      }
#pragma unroll
      for (int mt = 0; mt < 4; ++mt)
#pragma unroll
        for (int nt = 0; nt < 4; ++nt)
          acc[mt][nt] = MFMA16(af[mt], bf_[nt], acc[mt][nt]);
    }
    __syncthreads();
  }

#pragma unroll
  for (int mt = 0; mt < 4; ++mt) {
#pragma unroll
    for (int nt = 0; nt < 4; ++nt) {
      int n = n0 + wn * 64 + nt * 16 + qc;
      int head = n >> 6, d = n & 63;
      float bb = bias[n];
      int mB = m0 + wm * 64 + mt * 16 + 4 * g;
      int bidx = mB >> 12, s0 = mB & 4095;
      f32x4 a = acc[mt][nt];
      if (z == 2) {
        ushort4 o;
        o.x = f2bf(a[0] + bb); o.y = f2bf(a[1] + bb);
        o.z = f2bf(a[2] + bb); o.w = f2bf(a[3] + bb);
        // permuted storage column: (32K|16A|4G|B) -> (32K|8G|4A|B); B=0 here
        int scol = (s0 & ~31) | (((s0 >> 2) & 3) << 3) | (((s0 >> 4) & 1) << 2);
        *(ushort4*)&Vt[((size_t)((bidx * NH + head) * 64 + d)) * SEQ + scol] = o;
      } else {
        ushort_t* dst = (z == 0) ? Qh : Kh;
        float sc = (z == 0) ? QSCALE : 1.0f;
        size_t base = (size_t)(bidx * NH + head) * SEQ;
#pragma unroll
        for (int i = 0; i < 4; ++i)
          dst[(base + s0 + i) * 64 + d] = f2bf((a[i] + bb) * sc);
      }
    }
  }
}

// ---------------------------------------------------------------- kernel 4 helpers
// One K/V tile staged (4 DMAs); dest buffer passed as pointers (static).
__device__ __forceinline__ void stage_tile(const ushort_t* __restrict__ Kb,
                                           const ushort_t* __restrict__ Vb,
                                           ushort_t* Kd, ushort_t* Vd,
                                           int kb, const int* jr, const int* jc, int w) {
#pragma unroll
  for (int i = 0; i < 2; ++i) {
    gload_lds16(&Kb[(size_t)(kb + jr[i]) * 64 + jc[i] * 8], &Kd[(w * 128 + i * 64) * 8]);
    gload_lds16(&Vb[(size_t)jr[i] * SEQ + kb + jc[i] * 8], &Vd[(w * 128 + i * 64) * 8]);
  }
}

// One tile's compute, phase-split for in-wave ILP:
// QK(qf0) -> QK(qf1) -> exp2/pack(qf0) -> exp2/pack(qf1) -> fused PV.
// exp2(qf0) overlaps the matrix pipe draining qf1's MFMAs (round-6 body
// serialized QK(qf)->exp2(qf) per qf).  Value-for-value FP ops identical.
__device__ __forceinline__ void tile_compute(const ushort_t* Kc, const ushort_t* Vc,
                                             const bfrag (&qv)[2][2],
                                             f32x4 (&o)[2][4], f32x4 (&lacc)[2],
                                             bfrag ones, int g, int qc) {
  bfrag ak[4][2];
#pragma unroll
  for (int s = 0; s < 4; ++s) {
    const int r = s * 16 + qc;
    ak[s][0] = *(const bfrag*)&Kc[r * 64 + ((g ^ (qc & 7)) * 8)];
    ak[s][1] = *(const bfrag*)&Kc[r * 64 + (((4 + g) ^ (qc & 7)) * 8)];
  }
  f32x4 st0[4], st1[4];
#pragma unroll
  for (int s = 0; s < 4; ++s) {
    f32x4 z = zero4();
    z = MFMA16(ak[s][0], qv[0][0], z);
    st0[s] = MFMA16(ak[s][1], qv[0][1], z);
  }
#pragma unroll
  for (int s = 0; s < 4; ++s) {
    f32x4 z = zero4();
    z = MFMA16(ak[s][0], qv[1][0], z);
    st1[s] = MFMA16(ak[s][1], qv[1][1], z);
  }
  bfrag bp0[2], bp1[2];
#pragma unroll
  for (int i = 0; i < 4; ++i) {
    bp0[0][i]     = (__bf16)__builtin_amdgcn_exp2f(st0[0][i]);
    bp0[0][4 + i] = (__bf16)__builtin_amdgcn_exp2f(st0[1][i]);
    bp0[1][i]     = (__bf16)__builtin_amdgcn_exp2f(st0[2][i]);
    bp0[1][4 + i] = (__bf16)__builtin_amdgcn_exp2f(st0[3][i]);
  }
  lacc[0] = MFMA16(ones, bp0[0], lacc[0]);
  lacc[0] = MFMA16(ones, bp0[1], lacc[0]);
#pragma unroll
  for (int i = 0; i < 4; ++i) {
    bp1[0][i]     = (__bf16)__builtin_amdgcn_exp2f(st1[0][i]);
    bp1[0][4 + i] = (__bf16)__builtin_amdgcn_exp2f(st1[1][i]);
    bp1[1][i]     = (__bf16)__builtin_amdgcn_exp2f(st1[2][i]);
    bp1[1][4 + i] = (__bf16)__builtin_amdgcn_exp2f(st1[3][i]);
  }
  lacc[1] = MFMA16(ones, bp1[0], lacc[1]);
  lacc[1] = MFMA16(ones, bp1[1], lacc[1]);
#pragma unroll
  for (int kk = 0; kk < 2; ++kk) {
#pragma unroll
    for (int dt = 0; dt < 4; ++dt) {
      bfrag av = *(const bfrag*)&Vc[(dt * 16 + qc) * 64 + (((kk * 4 + g) ^ (qc & 7)) * 8)];
      o[0][dt] = MFMA16(av, bp0[kk], o[0][dt]);
      o[1][dt] = MFMA16(av, bp1[kk], o[1][dt]);
    }
  }
}

// ---------------------------------------------------------------- kernel 4
// Flash attention, no-max softmax, zero-shuffle P (V-permutation supplies
// the k-order the in-register P fragments carry).  Round-11: exact round-6
// structure (2 buffers, vmcnt(0)+barrier handoff, best measured 102.4us)
// with the kt loop UNROLLED BY 2 so every LDS address is a literal-buffer
// constant (kills dynamic `cur` addressing VALU), and the compute body
// phase-split for in-wave MFMA/VALU overlap (see tile_compute).
// Sync discipline unchanged: per-wave vmcnt(0) before every handoff barrier;
// stage-after-barrier targets the buffer whose readers passed that barrier;
// last tile (63) issues no staging -> nothing in flight at s_endpgm.
__global__ __launch_bounds__(256, 3) void attn_kernel(const ushort_t* __restrict__ Qh,
                                                      const ushort_t* __restrict__ Kh,
                                                      const ushort_t* __restrict__ Vt,
                                                      float* __restrict__ out) {
  const int bh = blockIdx.y;
  const int b = bh / NH, head = bh - b * NH;
  const int t = threadIdx.x, w = t >> 6, lane = t & 63;
  const int g = lane >> 4, qc = lane & 15;
  const ushort_t* Qb = Qh + (size_t)bh * SEQ * 64;
  const ushort_t* Kb = Kh + (size_t)bh * SEQ * 64;
  const ushort_t* Vb = Vt + (size_t)bh * 64 * SEQ;
  const int q0 = blockIdx.x * 128 + w * 32;

  __shared__ ushort_t Kls[2][4096];  // [buf][64 krow x 64 d], (r&7)-swizzled 16B chunks
  __shared__ ushort_t Vls[2][4096];  // [buf][64 d x 64 k],   (r&7)-swizzled 16B chunks

  int jr[2], jc[2];
#pragma unroll
  for (int i = 0; i < 2; ++i) {
    int j = w * 128 + i * 64 + lane;
    jr[i] = j >> 3;
    jc[i] = (j & 7) ^ (jr[i] & 7);
  }

  bfrag qv[2][2];
#pragma unroll
  for (int qf = 0; qf < 2; ++qf)
#pragma unroll
    for (int dd = 0; dd < 2; ++dd)
      qv[qf][dd] = *(const bfrag*)&Qb[(size_t)(q0 + qf * 16 + qc) * 64 + dd * 32 + g * 8];

  f32x4 o[2][4];
  f32x4 lacc[2];
#pragma unroll
  for (int qf = 0; qf < 2; ++qf) {
    lacc[qf] = zero4();
#pragma unroll
    for (int dt = 0; dt < 4; ++dt) o[qf][dt] = zero4();
  }
  bfrag ones;
#pragma unroll
  for (int j = 0; j < 8; ++j) ones[j] = (__bf16)1.0f;

  // prologue: stage tile 0 into buf 0
  stage_tile(Kb, Vb, &Kls[0][0], &Vls[0][0], 0, jr, jc, w);

  for (int kt2 = 0; kt2 < 32; ++kt2) {
    const int k0 = kt2 * 2;
    // ---- phase A: compute tile k0 from buf 0, prefetch k0+1 -> buf 1 ----
    WAIT_VMCNT0();
    __syncthreads();
    stage_tile(Kb, Vb, &Kls[1][0], &Vls[1][0], (k0 + 1) * 64, jr, jc, w);  // k0+1 <= 63 always
    tile_compute(&Kls[0][0], &Vls[0][0], qv, o, lacc, ones, g, qc);
    // ---- phase B: compute tile k0+1 from buf 1, prefetch k0+2 -> buf 0 ----
    WAIT_VMCNT0();
    __syncthreads();
    if (kt2 < 31)
      stage_tile(Kb, Vb, &Kls[0][0], &Vls[0][0], (k0 + 2) * 64, jr, jc, w);
    tile_compute(&Kls[1][0], &Vls[1][0], qv, o, lacc, ones, g, qc);
  }

  // epilogue: O^T layout row d = dt*16+4g+i, col q = qc; l identical in every reg
#pragma unroll
  for (int qf = 0; qf < 2; ++qf) {
    float inv = 1.0f / lacc[qf][0];
    int qrow = q0 + qf * 16 + qc;
    float* orow = out + (size_t)(b * SEQ + qrow) * HID + head * 64;
#pragma unroll
    for (int dt = 0; dt < 4; ++dt) {
      float4 vv;
      vv.x = o[qf][dt][0] * inv; vv.y = o[qf][dt][1] * inv;
      vv.z = o[qf][dt][2] * inv; vv.w = o[qf][dt][3] * inv;
      *(float4*)(orow + dt * 16 + 4 * g) = vv;
    }
  }
}

// ---------------------------------------------------------------- launch
extern "C" void kernel_launch(void* const* d_in, const int* in_sizes, int n_in,
                              void* d_out, int out_size, void* d_ws, size_t ws_size,
                              hipStream_t stream) {
  (void)in_sizes; (void)n_in; (void)out_size; (void)ws_size;
  const float* hs = (const float*)d_in[0];
  const float* Wq = (const float*)d_in[1];
  const float* bq = (const float*)d_in[2];
  const float* Wk = (const float*)d_in[3];
  const float* bk = (const float*)d_in[4];
  const float* Wv = (const float*)d_in[5];
  const float* bv = (const float*)d_in[6];
  float* out = (float*)d_out;

  char* ws = (char*)d_ws;
  ushort_t* Abf = (ushort_t*)ws;                               // 12582912 B
  ushort_t* Wt  = (ushort_t*)(ws + 12582912);                  //  3538944 B
  ushort_t* Qh  = (ushort_t*)(ws + 12582912 + 3538944);        // 12582912 B
  ushort_t* Kh  = Qh + 6291456;
  ushort_t* Vt  = Kh + 6291456;

  cvt_hidden<<<6144, 256, 0, stream>>>(hs, Abf);
  transpose_w<<<dim3(12, 12, 3), 256, 0, stream>>>(Wq, Wk, Wv, Wt);
  qkv_gemm<<<dim3(64, 6, 3), 256, 0, stream>>>(Abf, Wt, bq, bk, bv, Qh, Kh, Vt);
  attn_kernel<<<dim3(32, 24), 256, 0, stream>>>(Qh, Kh, Vt, out);
}